// Round 6
// baseline (225.056 us; speedup 1.0000x reference)
//
#include <hip/hip_runtime.h>

// Pixel-unshuffle 2x2 (space-to-depth), fp32.
// in : [32, 1, 2048, 2048]  out : [32, 4, 1024, 1024]
// out[b][2*(h&1) + (w&1)][h/2][w/2] = in[b][0][h][w]
//
// R6: LDS-staged transpose so BOTH global streams are dense float4
// (R4 lesson: lane-adjacent must be address-adjacent; R5 lesson: x2 stores
// cost ~3%). Block = 256 threads, chunk = 2 input rows (4096 floats) =
// 4 output plane-rows of 1024 floats (planes 4b..4b+3, out row kk).
//   load : 4x dense float4/thread (1KB/instr), nt.
//   LDS  : scatter ev=(x,z), od=(y,w) as float2 into plane-ordered LDS.
//          lanes stride 8B -> 2-way bank alias = free (m136).
//   read : 4x dense ds_read_b128 (each = one plane-row slice).
//   store: 4x dense float4/thread (1KB/instr, whole wave one plane), nt.
// 16 KB LDS, 2 barriers/iter -> 8 blocks/CU (thread-capped), max TLP.

typedef float f32x4 __attribute__((ext_vector_type(4)));
typedef float f32x2 __attribute__((ext_vector_type(2)));

__global__ __launch_bounds__(256) void pixel_unshuffle_lds(
    const f32x4* __restrict__ in4, f32x4* __restrict__ out4, int nchunk) {
    __shared__ alignas(16) f32x2 lds[2048];  // 4 plane-rows x 512 f32x2 = 16KB
    const int tid = threadIdx.x;

    for (int k = blockIdx.x; k < nchunk; k += gridDim.x) {
        const int b  = k >> 10;    // image
        const int kk = k & 1023;   // output row (input rows 2kk, 2kk+1)
        const f32x4* src = in4 + ((long)k << 10);  // 1024 f32x4 per chunk

        // Dense loads: float4 #m, m = 256q + tid (floats 4m..4m+3).
        const f32x4 v0 = __builtin_nontemporal_load(src + tid);
        const f32x4 v1 = __builtin_nontemporal_load(src + 256 + tid);
        const f32x4 v2 = __builtin_nontemporal_load(src + 512 + tid);
        const f32x4 v3 = __builtin_nontemporal_load(src + 768 + tid);

        // Scatter: float4 #m -> row parity hp=m>>9, ev cols (2m,2m+1) of
        // plane 2hp, od same cols of plane 2hp+1. Plane p = f32x2 range
        // [512p, 512p+512). ev f32x2 idx = 1024*hp + (m&511); od = +512.
#define WR(v, q)                                                   \
        {                                                          \
            const int m  = ((q) << 8) + tid;                       \
            const int ei = ((m >> 9) << 10) + (m & 511);           \
            f32x2 ev, od;                                          \
            ev.x = (v).x; ev.y = (v).z;                            \
            od.x = (v).y; od.y = (v).w;                            \
            lds[ei]       = ev;                                    \
            lds[ei + 512] = od;                                    \
        }
        WR(v0, 0) WR(v1, 1) WR(v2, 2) WR(v3, 3)
#undef WR

        __syncthreads();

        // Dense reads: plane r's row slice, float4 #(256r + tid).
        const f32x4* Lr = (const f32x4*)lds;
        const f32x4 o0 = Lr[tid];
        const f32x4 o1 = Lr[256 + tid];
        const f32x4 o2 = Lr[512 + tid];
        const f32x4 o3 = Lr[768 + tid];

        // Dense stores: plane (4b+r), row kk. Plane = 1<<18 f32x4,
        // row = 256 f32x4.
        f32x4* dst = out4 + (((long)(b << 2)) << 18) + (kk << 8) + tid;
        __builtin_nontemporal_store(o0, dst);
        __builtin_nontemporal_store(o1, dst + (1 << 18));
        __builtin_nontemporal_store(o2, dst + (2 << 18));
        __builtin_nontemporal_store(o3, dst + (3 << 18));

        __syncthreads();  // protect LDS reuse next iteration
    }
}

extern "C" void kernel_launch(void* const* d_in, const int* in_sizes, int n_in,
                              void* d_out, int out_size, void* d_ws, size_t ws_size,
                              hipStream_t stream) {
    const f32x4* in4 = (const f32x4*)d_in[0];
    f32x4* out4      = (f32x4*)d_out;

    const int nchunk = 32 * 1024;  // 2-row chunks: 32 images x 1024
    const int block  = 256;
    const int grid   = 2048;       // 16 chunks per block

    pixel_unshuffle_lds<<<grid, block, 0, stream>>>(in4, out4, nchunk);
}

// Round 7
// 221.385 us; speedup vs baseline: 1.0166x; 1.0166x over previous
//
#include <hip/hip_runtime.h>

// Pixel-unshuffle 2x2 (space-to-depth), fp32.
// in : [32, 1, 2048, 2048]  out : [32, 4, 1024, 1024]
// out[b][2*(h&1) + (w&1)][h/2][w/2] = in[b][0][h][w]
//
// R7: wave-private LDS transpose, ZERO barriers (R6 lesson: __syncthreads
// drained the load pipe). DS ops of one wave complete in order, so an
// inline s_waitcnt lgkmcnt(0) is the only fence needed.
// Per wave-iteration (2 chunks of 512 consecutive floats = half input row):
//   load : 4x dense f32x4 (1KB/instr), nt
//   LDS  : 8x ds_write_b64 scatter (ev|od areas; stride-8B lanes = 2-way
//          bank alias = free, m136)
//   fence: lgkmcnt(0) only — vmcnt untouched, so the manually-pipelined
//          next-pair global loads stay in flight through LDS+store phase
//   read : 4x dense ds_read_b128
//   store: 4x dense f32x4 (1KB/instr, whole wave one plane row), nt
// 16 KB LDS/block, no inter-wave coupling at all.

typedef float f32x4 __attribute__((ext_vector_type(4)));
typedef float f32x2 __attribute__((ext_vector_type(2)));

#define NTL(p)    __builtin_nontemporal_load(p)
#define NTS(v, p) __builtin_nontemporal_store(v, p)

// Chunk c = 512 consecutive floats = quarter of input row (row r = c>>2,
// quarter q = c&3) -> 64 f32x4 of plane cb (ev) + 64 of cb+1 (od),
// out row i = h>>1, f32x4 cols [64q, 64q+64).
__device__ __forceinline__ int ev_off(int c, int lane) {
    const int row = c >> 2;     // b*2048 + h
    const int q   = c & 3;
    const int h   = row & 2047;
    const int b   = row >> 11;
    const int i   = h >> 1;
    const int cb  = (h & 1) << 1;
    // f32x4 units: plane = 1<<18, out row = 1<<8
    return (((b << 2) + cb) << 18) + (i << 8) + (q << 6) + lane;
}

__global__ __launch_bounds__(256) void pixel_unshuffle_ws(
    const f32x4* __restrict__ in4, f32x4* __restrict__ out4, int nchunk) {
    __shared__ alignas(16) f32x2 lds2[2048];  // 4 waves x 512 f32x2 = 16 KB
    const int tid  = threadIdx.x;
    const int wid  = tid >> 6;
    const int lane = tid & 63;
    f32x2* W        = lds2 + (wid << 9);      // wave-private 4 KB
    const f32x4* W4 = (const f32x4*)W;

    const int gw     = (blockIdx.x << 2) + wid;  // global wave id
    const int stride = gridDim.x << 3;           // nwaves * 2 chunks

    int c = gw << 1;
    if (c >= nchunk) return;

    f32x4 v0 = NTL(in4 + (c << 7) + lane);
    f32x4 v1 = NTL(in4 + (c << 7) + 64 + lane);
    f32x4 v2 = NTL(in4 + (c << 7) + 128 + lane);
    f32x4 v3 = NTL(in4 + (c << 7) + 192 + lane);

    while (true) {
        // Compiler barrier: keep these writes below last iter's ds_reads.
        asm volatile("" ::: "memory");

        // Scatter pair into wave LDS. Chunk A: ev [0,128) od [128,256);
        // chunk B: ev [256,384) od [384,512)  (f32x2 units).
        f32x2 t;
        t.x = v0.x; t.y = v0.z; W[lane]       = t;
        t.x = v0.y; t.y = v0.w; W[lane + 128] = t;
        t.x = v1.x; t.y = v1.z; W[lane + 64]  = t;
        t.x = v1.y; t.y = v1.w; W[lane + 192] = t;
        t.x = v2.x; t.y = v2.z; W[lane + 256] = t;
        t.x = v2.y; t.y = v2.w; W[lane + 384] = t;
        t.x = v3.x; t.y = v3.z; W[lane + 320] = t;
        t.x = v3.y; t.y = v3.w; W[lane + 448] = t;

        // Prefetch next pair BEFORE the lgkm fence (vmcnt unaffected).
        const int cn   = c + stride;
        const bool more = (cn < nchunk);   // wave-uniform
        f32x4 u0, u1, u2, u3;
        if (more) {
            u0 = NTL(in4 + (cn << 7) + lane);
            u1 = NTL(in4 + (cn << 7) + 64 + lane);
            u2 = NTL(in4 + (cn << 7) + 128 + lane);
            u3 = NTL(in4 + (cn << 7) + 192 + lane);
        }

        asm volatile("s_waitcnt lgkmcnt(0)" ::: "memory");
        __builtin_amdgcn_sched_barrier(0);

        // Dense gather: f32x4 entry L of each area.
        const f32x4 e0 = W4[lane];        // chunk A ev
        const f32x4 o0 = W4[lane + 64];   // chunk A od
        const f32x4 e1 = W4[lane + 128];  // chunk B ev
        const f32x4 o1 = W4[lane + 192];  // chunk B od

        const int ea = ev_off(c, lane);
        NTS(e0, out4 + ea);
        NTS(o0, out4 + ea + (1 << 18));
        const int eb = ev_off(c + 1, lane);
        NTS(e1, out4 + eb);
        NTS(o1, out4 + eb + (1 << 18));

        if (!more) break;
        v0 = u0; v1 = u1; v2 = u2; v3 = u3;
        c = cn;
    }
}

extern "C" void kernel_launch(void* const* d_in, const int* in_sizes, int n_in,
                              void* d_out, int out_size, void* d_ws, size_t ws_size,
                              hipStream_t stream) {
    const f32x4* in4 = (const f32x4*)d_in[0];
    f32x4* out4      = (f32x4*)d_out;

    const int nchunk = 32 * 2048 * 4;  // 512-float chunks: 131072
    const int block  = 256;
    const int grid   = 2048;           // 8192 waves, 8 pair-iterations each

    pixel_unshuffle_ws<<<grid, block, 0, stream>>>(in4, out4, nchunk);
}

// Round 8
// 202.538 us; speedup vs baseline: 1.1112x; 1.0931x over previous
//
#include <hip/hip_runtime.h>

// Pixel-unshuffle 2x2 (space-to-depth), fp32.
// in : [32, 1, 2048, 2048]  out : [32, 4, 1024, 1024]
// out[b][2*(h&1) + (w&1)][h/2][w/2] = in[b][0][h][w]
//
// TERMINAL (R3 structure, best of 7 variants at 202 us = 5.32 TB/s eff).
// Each thread owns 8 consecutive input floats (2x f32x4, 32B lane stride):
// evens -> one dense f32x4 in plane cbase, odds -> one dense f32x4 in plane
// cbase+1. Stores fully coalesced (1KB/instr). 4 items/thread/iter = 8 loads
// in flight before stores (vmcnt FIFO amortization). nt hints on both sides
// (touch-once streams >> 256MB L3).
//
// Why not "better": dense-load variants must pay elsewhere —
//   x2 stores (R5: 208us), shfl + interleaved stores (R4: 219us),
//   LDS staging w/ barriers (R6: 225us), wave-private LDS no barriers
//   (R7: 221us). The 2x2 gather provably can't have per-instruction-dense
//   loads AND x4-dense lane-local stores without cross-lane movement.

typedef float f32x4 __attribute__((ext_vector_type(4)));

__device__ __forceinline__ void unshuffle_item(
    int t, f32x4 a, f32x4 c, f32x4* __restrict__ out4) {
    const int wi  = t & 255;   // item within row (256 items * 8 floats = 2048)
    const int row = t >> 8;    // b*2048 + h
    const int h   = row & 2047;
    const int b   = row >> 11;

    f32x4 ev, od;
    ev.x = a.x; ev.y = a.z; ev.z = c.x; ev.w = c.z;
    od.x = a.y; od.y = a.w; od.z = c.y; od.w = c.w;

    const int i     = h >> 1;
    const int cbase = (h & 1) << 1;
    // float4-unit offsets: out plane = 262144 float4, out row = 256 float4
    const int obase = (((b << 2) + cbase) << 18) + (i << 8) + wi;

    __builtin_nontemporal_store(ev, out4 + obase);           // channel cbase
    __builtin_nontemporal_store(od, out4 + obase + 262144);  // channel cbase+1
}

__global__ __launch_bounds__(256) void pixel_unshuffle_kernel(
    const f32x4* __restrict__ in4, f32x4* __restrict__ out4, int n_items) {
    const int tpb  = 256;
    const int span = gridDim.x * tpb * 4;  // items covered per sweep
    for (int base = blockIdx.x * tpb * 4 + threadIdx.x; base < n_items;
         base += span) {
        const int t0 = base;
        const int t1 = base + tpb;      // n_items % span == 0 for this shape
        const int t2 = base + 2 * tpb;
        const int t3 = base + 3 * tpb;

        // Issue all 8 loads before any dependent use.
        const f32x4 a0 = __builtin_nontemporal_load(in4 + 2 * t0);
        const f32x4 c0 = __builtin_nontemporal_load(in4 + 2 * t0 + 1);
        const f32x4 a1 = __builtin_nontemporal_load(in4 + 2 * t1);
        const f32x4 c1 = __builtin_nontemporal_load(in4 + 2 * t1 + 1);
        const f32x4 a2 = __builtin_nontemporal_load(in4 + 2 * t2);
        const f32x4 c2 = __builtin_nontemporal_load(in4 + 2 * t2 + 1);
        const f32x4 a3 = __builtin_nontemporal_load(in4 + 2 * t3);
        const f32x4 c3 = __builtin_nontemporal_load(in4 + 2 * t3 + 1);

        unshuffle_item(t0, a0, c0, out4);
        unshuffle_item(t1, a1, c1, out4);
        unshuffle_item(t2, a2, c2, out4);
        unshuffle_item(t3, a3, c3, out4);
    }
}

extern "C" void kernel_launch(void* const* d_in, const int* in_sizes, int n_in,
                              void* d_out, int out_size, void* d_ws, size_t ws_size,
                              hipStream_t stream) {
    const f32x4* in4 = (const f32x4*)d_in[0];
    f32x4* out4      = (f32x4*)d_out;

    const int n_items = 32 * 2048 * 2048 / 8;  // 16,777,216 items of 8 floats
    const int block   = 256;
    const int grid    = 2048;  // 8 sweeps of the grid-stride loop

    pixel_unshuffle_kernel<<<grid, block, 0, stream>>>(in4, out4, n_items);
}